// Round 8
// baseline (4648.898 us; speedup 1.0000x reference)
//
#include <hip/hip_runtime.h>
#include <hip/hip_bf16.h>
#include <hip/hip_fp16.h>

#define T_ 1024
#define B_ 32
#define H_ 256
#define G3 768   // 3*H

__device__ __forceinline__ float sigmoidf_(float x) { return 1.f / (1.f + __expf(-x)); }
__device__ __forceinline__ float tanhf_(float x) {
    float e = __expf(2.f * x);
    return (e - 1.f) / (e + 1.f);
}

// LDS-only barrier: does NOT drain vmcnt (global prefetch loads / out stores
// stay in flight across it).
__device__ __forceinline__ void sync_lds() {
    asm volatile("s_waitcnt lgkmcnt(0)" ::: "memory");
    asm volatile("s_barrier" ::: "memory");
}

// Native packed f16 dot-2 with fp32 accumulate, VGPR operands forced.
__device__ __forceinline__ void dot2a(float& acc, unsigned w, unsigned h) {
    asm("v_dot2_f32_f16 %0, %1, %2, %0" : "+v"(acc) : "v"(w), "v"(h));
}

__device__ __forceinline__ unsigned pack_f16rn(float x, float y) {
    unsigned short ux = __half_as_ushort(__float2half_rn(x));
    unsigned short uy = __half_as_ushort(__float2half_rn(y));
    return (unsigned)ux | ((unsigned)uy << 16);
}

// C[M,N] = A[M,K] @ W[N,K]^T + bias[N]
template <typename CT>
__global__ __launch_bounds__(256) void gemm_bias_nt(
    const float* __restrict__ A, const float* __restrict__ W,
    const float* __restrict__ bias, CT* __restrict__ C,
    int M, int N, int K)
{
    __shared__ float As[16][68];
    __shared__ float Ws[16][68];
    const int tid = threadIdx.x;
    const int bm = blockIdx.y * 64;
    const int bn = blockIdx.x * 64;
    const int lr = tid & 63;
    const int lc = tid >> 6;
    const int tx = tid & 15;
    const int ty = tid >> 4;

    const float* Ap = A + (size_t)(bm + lr) * K + lc * 4;
    const float* Wp = W + (size_t)(bn + lr) * K + lc * 4;

    float acc[4][4];
#pragma unroll
    for (int i = 0; i < 4; ++i)
#pragma unroll
        for (int j = 0; j < 4; ++j) acc[i][j] = 0.f;

    for (int k0 = 0; k0 < K; k0 += 16) {
        float4 av = *(const float4*)(Ap + k0);
        float4 wv = *(const float4*)(Wp + k0);
        __syncthreads();
        As[lc * 4 + 0][lr] = av.x; As[lc * 4 + 1][lr] = av.y;
        As[lc * 4 + 2][lr] = av.z; As[lc * 4 + 3][lr] = av.w;
        Ws[lc * 4 + 0][lr] = wv.x; Ws[lc * 4 + 1][lr] = wv.y;
        Ws[lc * 4 + 2][lr] = wv.z; Ws[lc * 4 + 3][lr] = wv.w;
        __syncthreads();
#pragma unroll
        for (int kk = 0; kk < 16; ++kk) {
            float4 a4 = *(const float4*)&As[kk][ty * 4];
            float4 w4 = *(const float4*)&Ws[kk][tx * 4];
            float am[4] = {a4.x, a4.y, a4.z, a4.w};
            float wn[4] = {w4.x, w4.y, w4.z, w4.w};
#pragma unroll
            for (int i = 0; i < 4; ++i)
#pragma unroll
                for (int j = 0; j < 4; ++j) acc[i][j] += am[i] * wn[j];
        }
    }

#pragma unroll
    for (int i = 0; i < 4; ++i) {
        size_t cbase = (size_t)(bm + ty * 4 + i) * N + bn + tx * 4;
#pragma unroll
        for (int j = 0; j < 4; ++j) {
            float v = acc[i][j] + bias[bn + tx * 4 + j];
            C[cbase + j] = (CT)v;
        }
    }
}

// One WG per (batch, direction), 1024 threads = 16 waves, 4 waves/SIMD.
// Thread map: j = (tid>>6)*16 + (lane&15) in 0..255, kq = lane>>4 in 0..3.
// Thread owns W_hh rows j, j+256, j+512 over K-quarter [kq*64, kq*64+64):
// 96 u32 of packed f16x2 -> fits the 128-VGPR/4-wave budget in ARCH VGPRs
// (no AGPR headroom exists at 4 waves/SIMD, so no unified-file split).
// Cross-K reduce = shfl_xor(16)+shfl_xor(32) in-wave -> ONE barrier/step.
// h16 double-buffered; quarters staggered at 72-f16 stride so the 4 kq
// broadcast groups start on banks {0,4,8,12} (conflict-free ds_read_b128).
template <typename PT>
__global__ __launch_bounds__(1024, 4) void gru_scan_q(
    const PT* __restrict__ Pf, const PT* __restrict__ Pb,
    const float* __restrict__ Wf, const float* __restrict__ Wb,
    const float* __restrict__ bhf, const float* __restrict__ bhb,
    const int* __restrict__ lengths,
    float* __restrict__ out,   // (T,B,512)
    float* __restrict__ hn,    // [dir][b][j]
    int do_mask)
{
    const int b = blockIdx.x >> 1;
    const int dir = blockIdx.x & 1;
    const PT* P = dir ? Pb : Pf;
    const float* W = dir ? Wb : Wf;
    const float* bh = dir ? bhb : bhf;
    const int len = lengths[b];

    __shared__ __align__(16) unsigned short h16[2][288];  // 4 quarters @ stride 72

    const int tid = threadIdx.x;
    const int lane = tid & 63;
    const int j = (tid >> 6) * 16 + (lane & 15);
    const int kq = lane >> 4;

    // ---- load W_hh (3 rows x K-quarter) into 96 arch VGPRs ----
    unsigned wr[32], wz[32], wn[32];
    {
        const float4* r0 = (const float4*)(W + (size_t)j * H_ + kq * 64);
        const float4* r1 = (const float4*)(W + (size_t)(j + 256) * H_ + kq * 64);
        const float4* r2 = (const float4*)(W + (size_t)(j + 512) * H_ + kq * 64);
#pragma unroll
        for (int q = 0; q < 16; ++q) {
            float4 a = r0[q]; wr[2 * q] = pack_f16rn(a.x, a.y); wr[2 * q + 1] = pack_f16rn(a.z, a.w);
            float4 c = r1[q]; wz[2 * q] = pack_f16rn(c.x, c.y); wz[2 * q + 1] = pack_f16rn(c.z, c.w);
            float4 d = r2[q]; wn[2 * q] = pack_f16rn(d.x, d.y); wn[2 * q + 1] = pack_f16rn(d.z, d.w);
            __builtin_amdgcn_sched_barrier(0);
        }
    }

    const float bh0 = bh[j];
    const float bh1 = bh[j + 256];
    const float bh2 = bh[j + 512];

    float hreg = 0.f;
    if (tid < 288) h16[0][tid] = 0;

    float* outp = out + (size_t)b * 512 + dir * 256;
    float* hnp = hn + (size_t)dir * (B_ * H_) + (size_t)b * H_;

    int crow = dir ? ((len - 1) & (T_ - 1)) : 0;   // row of current step
    int prow = dir ? ((len - 2) & (T_ - 1)) : 1;   // row of next step (prefetch)
    const int rstep = dir ? -1 : 1;
    const PT* Pbase = P + (size_t)b * G3 + j;

    // prologue: P for step 0
    float cir, ciz, cin;
    {
        const PT* pp = Pbase + (size_t)crow * (B_ * G3);
        cir = (float)pp[0]; ciz = (float)pp[256]; cin = (float)pp[512];
    }
    sync_lds();

#pragma unroll 1
    for (int s = 0; s < T_; ++s) {
        // prefetch next step's P (stays in flight across the barrier)
        float nir, niz, nin;
        {
            const PT* pp = Pbase + (size_t)prow * (B_ * G3);
            nir = (float)pp[0]; niz = (float)pp[256]; nin = (float)pp[512];
        }

        // ---- matvec over this thread's K-quarter (96 native v_dot2) ----
        float ar0 = 0.f, az0 = 0.f, an0 = 0.f;
        float ar1 = 0.f, az1 = 0.f, an1 = 0.f;
        const uint4* hv = (const uint4*)(&h16[s & 1][kq * 72]);
#pragma unroll
        for (int m = 0; m < 8; ++m) {
            uint4 u = hv[m];
            if (m & 1) {
                dot2a(ar1, wr[4 * m + 0], u.x); dot2a(az1, wz[4 * m + 0], u.x); dot2a(an1, wn[4 * m + 0], u.x);
                dot2a(ar1, wr[4 * m + 1], u.y); dot2a(az1, wz[4 * m + 1], u.y); dot2a(an1, wn[4 * m + 1], u.y);
                dot2a(ar1, wr[4 * m + 2], u.z); dot2a(az1, wz[4 * m + 2], u.z); dot2a(an1, wn[4 * m + 2], u.z);
                dot2a(ar1, wr[4 * m + 3], u.w); dot2a(az1, wz[4 * m + 3], u.w); dot2a(an1, wn[4 * m + 3], u.w);
            } else {
                dot2a(ar0, wr[4 * m + 0], u.x); dot2a(az0, wz[4 * m + 0], u.x); dot2a(an0, wn[4 * m + 0], u.x);
                dot2a(ar0, wr[4 * m + 1], u.y); dot2a(az0, wz[4 * m + 1], u.y); dot2a(an0, wn[4 * m + 1], u.y);
                dot2a(ar0, wr[4 * m + 2], u.z); dot2a(az0, wz[4 * m + 2], u.z); dot2a(an0, wn[4 * m + 2], u.z);
                dot2a(ar0, wr[4 * m + 3], u.w); dot2a(az0, wz[4 * m + 3], u.w); dot2a(an0, wn[4 * m + 3], u.w);
            }
            __builtin_amdgcn_sched_barrier(0);
        }
        float ar = ar0 + ar1;
        float az = az0 + az1;
        float an = an0 + an1;
        // cross-quarter reduce: partners are lane^16 and lane^32
        ar += __shfl_xor(ar, 16); az += __shfl_xor(az, 16); an += __shfl_xor(an, 16);
        ar += __shfl_xor(ar, 32); az += __shfl_xor(az, 32); an += __shfl_xor(an, 32);

        // ---- epilogue (redundant across kq; bitwise identical) ----
        float r = sigmoidf_(cir + ar + bh0);
        float z = sigmoidf_(ciz + az + bh1);
        float nng = tanhf_(cin + r * (an + bh2));
        float hnew = (1.f - z) * nng + z * hreg;
        hreg = hnew;

        if (kq == 0) {   // one lane-group stores
            h16[(s & 1) ^ 1][(j >> 6) * 72 + (j & 63)] = __half_as_ushort(__float2half_rn(hnew));
            float ov = (do_mask && crow >= len) ? 0.f : hnew;
            outp[(size_t)crow * (B_ * 512) + j] = ov;
            if (s == len - 1) hnp[j] = hnew;
        }
        sync_lds();   // the one barrier per step

        cir = nir; ciz = niz; cin = nin;
        crow = (crow + rstep) & (T_ - 1);
        prow = (prow + rstep) & (T_ - 1);
    }
}

extern "C" void kernel_launch(void* const* d_in, const int* in_sizes, int n_in,
                              void* d_out, int out_size, void* d_ws, size_t ws_size,
                              hipStream_t stream)
{
    const float* x        = (const float*)d_in[0];
    const float* w_ih_l0f = (const float*)d_in[1];
    const float* w_hh_l0f = (const float*)d_in[2];
    const float* b_ih_l0f = (const float*)d_in[3];
    const float* b_hh_l0f = (const float*)d_in[4];
    const float* w_ih_l0b = (const float*)d_in[5];
    const float* w_hh_l0b = (const float*)d_in[6];
    const float* b_ih_l0b = (const float*)d_in[7];
    const float* b_hh_l0b = (const float*)d_in[8];
    const float* w_ih_l1f = (const float*)d_in[9];
    const float* w_hh_l1f = (const float*)d_in[10];
    const float* b_ih_l1f = (const float*)d_in[11];
    const float* b_hh_l1f = (const float*)d_in[12];
    const float* w_ih_l1b = (const float*)d_in[13];
    const float* w_hh_l1b = (const float*)d_in[14];
    const float* b_ih_l1b = (const float*)d_in[15];
    const float* b_hh_l1b = (const float*)d_in[16];
    const int*   lengths  = (const int*)d_in[17];

    float* out = (float*)d_out;
    const size_t OUT_OFF = (size_t)T_ * B_ * 512;
    float* hn0 = out + OUT_OFF;
    float* hn1 = hn0 + 2 * B_ * H_;

    const size_t PE = (size_t)T_ * B_ * G3;
    const int M = T_ * B_;
    dim3 gg(G3 / 64, M / 64);

    if (ws_size >= 2 * PE * sizeof(float)) {
        float* P0 = (float*)d_ws;
        float* P1 = P0 + PE;
        gemm_bias_nt<float><<<gg, 256, 0, stream>>>(x, w_ih_l0f, b_ih_l0f, P0, M, G3, 256);
        gemm_bias_nt<float><<<gg, 256, 0, stream>>>(x, w_ih_l0b, b_ih_l0b, P1, M, G3, 256);
        gru_scan_q<float><<<64, 1024, 0, stream>>>(P0, P1, w_hh_l0f, w_hh_l0b,
                                                   b_hh_l0f, b_hh_l0b, lengths, out, hn0, 0);
        gemm_bias_nt<float><<<gg, 256, 0, stream>>>(out, w_ih_l1f, b_ih_l1f, P0, M, G3, 512);
        gemm_bias_nt<float><<<gg, 256, 0, stream>>>(out, w_ih_l1b, b_ih_l1b, P1, M, G3, 512);
        gru_scan_q<float><<<64, 1024, 0, stream>>>(P0, P1, w_hh_l1f, w_hh_l1b,
                                                   b_hh_l1f, b_hh_l1b, lengths, out, hn1, 1);
    } else if (ws_size >= 2 * PE * sizeof(__hip_bfloat16)) {
        __hip_bfloat16* P0 = (__hip_bfloat16*)d_ws;
        __hip_bfloat16* P1 = P0 + PE;
        gemm_bias_nt<__hip_bfloat16><<<gg, 256, 0, stream>>>(x, w_ih_l0f, b_ih_l0f, P0, M, G3, 256);
        gemm_bias_nt<__hip_bfloat16><<<gg, 256, 0, stream>>>(x, w_ih_l0b, b_ih_l0b, P1, M, G3, 256);
        gru_scan_q<__hip_bfloat16><<<64, 1024, 0, stream>>>(P0, P1, w_hh_l0f, w_hh_l0b,
                                                            b_hh_l0f, b_hh_l0b, lengths, out, hn0, 0);
        gemm_bias_nt<__hip_bfloat16><<<gg, 256, 0, stream>>>(out, w_ih_l1f, b_ih_l1f, P0, M, G3, 512);
        gemm_bias_nt<__hip_bfloat16><<<gg, 256, 0, stream>>>(out, w_ih_l1b, b_ih_l1b, P1, M, G3, 512);
        gru_scan_q<__hip_bfloat16><<<64, 1024, 0, stream>>>(P0, P1, w_hh_l1f, w_hh_l1b,
                                                            b_hh_l1f, b_hh_l1b, lengths, out, hn1, 1);
    }
}

// Round 9
// 3986.000 us; speedup vs baseline: 1.1663x; 1.1663x over previous
//
#include <hip/hip_runtime.h>
#include <hip/hip_bf16.h>
#include <hip/hip_fp16.h>

#define T_ 1024
#define B_ 32
#define H_ 256
#define G3 768   // 3*H

__device__ __forceinline__ float sigmoidf_(float x) { return 1.f / (1.f + __expf(-x)); }
__device__ __forceinline__ float tanhf_(float x) {
    float e = __expf(2.f * x);
    return (e - 1.f) / (e + 1.f);
}

// LDS-only barrier: does NOT drain vmcnt (global prefetch loads / out stores
// stay in flight across it).
__device__ __forceinline__ void sync_lds() {
    asm volatile("s_waitcnt lgkmcnt(0)" ::: "memory");
    asm volatile("s_barrier" ::: "memory");
}

// Packed f16 FMA: acc.{lo,hi} += w.{lo,hi} * h.{lo,hi}  (full-rate VOP3P)
__device__ __forceinline__ void pkfma(unsigned& acc, unsigned w, unsigned h) {
    asm("v_pk_fma_f16 %0, %1, %2, %0" : "+v"(acc) : "v"(w), "v"(h));
}

__device__ __forceinline__ float lo16f(unsigned u) {
    return (float)__ushort_as_half((unsigned short)(u & 0xffffu));
}
__device__ __forceinline__ float hi16f(unsigned u) {
    return (float)__ushort_as_half((unsigned short)(u >> 16));
}

__device__ __forceinline__ unsigned pack_f16rn(float x, float y) {
    unsigned short ux = __half_as_ushort(__float2half_rn(x));
    unsigned short uy = __half_as_ushort(__float2half_rn(y));
    return (unsigned)ux | ((unsigned)uy << 16);
}

// C[M,N] = A[M,K] @ W[N,K]^T + bias[N]
template <typename CT>
__global__ __launch_bounds__(256) void gemm_bias_nt(
    const float* __restrict__ A, const float* __restrict__ W,
    const float* __restrict__ bias, CT* __restrict__ C,
    int M, int N, int K)
{
    __shared__ float As[16][68];
    __shared__ float Ws[16][68];
    const int tid = threadIdx.x;
    const int bm = blockIdx.y * 64;
    const int bn = blockIdx.x * 64;
    const int lr = tid & 63;
    const int lc = tid >> 6;
    const int tx = tid & 15;
    const int ty = tid >> 4;

    const float* Ap = A + (size_t)(bm + lr) * K + lc * 4;
    const float* Wp = W + (size_t)(bn + lr) * K + lc * 4;

    float acc[4][4];
#pragma unroll
    for (int i = 0; i < 4; ++i)
#pragma unroll
        for (int j = 0; j < 4; ++j) acc[i][j] = 0.f;

    for (int k0 = 0; k0 < K; k0 += 16) {
        float4 av = *(const float4*)(Ap + k0);
        float4 wv = *(const float4*)(Wp + k0);
        __syncthreads();
        As[lc * 4 + 0][lr] = av.x; As[lc * 4 + 1][lr] = av.y;
        As[lc * 4 + 2][lr] = av.z; As[lc * 4 + 3][lr] = av.w;
        Ws[lc * 4 + 0][lr] = wv.x; Ws[lc * 4 + 1][lr] = wv.y;
        Ws[lc * 4 + 2][lr] = wv.z; Ws[lc * 4 + 3][lr] = wv.w;
        __syncthreads();
#pragma unroll
        for (int kk = 0; kk < 16; ++kk) {
            float4 a4 = *(const float4*)&As[kk][ty * 4];
            float4 w4 = *(const float4*)&Ws[kk][tx * 4];
            float am[4] = {a4.x, a4.y, a4.z, a4.w};
            float wn[4] = {w4.x, w4.y, w4.z, w4.w};
#pragma unroll
            for (int i = 0; i < 4; ++i)
#pragma unroll
                for (int j = 0; j < 4; ++j) acc[i][j] += am[i] * wn[j];
        }
    }

#pragma unroll
    for (int i = 0; i < 4; ++i) {
        size_t cbase = (size_t)(bm + ty * 4 + i) * N + bn + tx * 4;
#pragma unroll
        for (int j = 0; j < 4; ++j) {
            float v = acc[i][j] + bias[bn + tx * 4 + j];
            C[cbase + j] = (CT)v;
        }
    }
}

// One WG per (batch, direction), 512 threads = 8 waves.
// Thread map: j = wave*32 + (lane&31), kh = lane>>5; K-half partner = lane^32
// (same wave) -> cross-K reduce is one shfl_xor(32), ONE barrier per step.
// Identical structure to R7 EXCEPT the MAC instruction: v_pk_fma_f16
// (packed-math full-rate path) with packed-f16 accumulators, replacing
// v_dot2_f32_f16 (suspected quarter-rate). Controlled A/B on the MAC op.
template <typename PT>
__global__ __launch_bounds__(512, 2) void gru_scan_pk(
    const PT* __restrict__ Pf, const PT* __restrict__ Pb,
    const float* __restrict__ Wf, const float* __restrict__ Wb,
    const float* __restrict__ bhf, const float* __restrict__ bhb,
    const int* __restrict__ lengths,
    float* __restrict__ out,   // (T,B,512)
    float* __restrict__ hn,    // [dir][b][j]
    int do_mask)
{
    const int b = blockIdx.x >> 1;
    const int dir = blockIdx.x & 1;
    const PT* P = dir ? Pb : Pf;
    const float* W = dir ? Wb : Wf;
    const float* bh = dir ? bhb : bhf;
    const int len = lengths[b];

    __shared__ __align__(16) unsigned short h16[2][H_];  // double-buffered h

    const int tid = threadIdx.x;
    const int lane = tid & 63;
    const int wave = tid >> 6;
    const int j = wave * 32 + (lane & 31);
    const int kh = lane >> 5;

    // ---- load W_hh rows j, j+256, j+512 (K-half) into registers ----
    unsigned wr[64], wz[64], wn[64];
    {
        const float4* r0 = (const float4*)(W + (size_t)j * H_ + kh * 128);
        const float4* r1 = (const float4*)(W + (size_t)(j + 256) * H_ + kh * 128);
        const float4* r2 = (const float4*)(W + (size_t)(j + 512) * H_ + kh * 128);
#pragma unroll
        for (int q = 0; q < 32; ++q) {
            float4 a = r0[q]; wr[2 * q] = pack_f16rn(a.x, a.y); wr[2 * q + 1] = pack_f16rn(a.z, a.w);
            float4 c = r1[q]; wz[2 * q] = pack_f16rn(c.x, c.y); wz[2 * q + 1] = pack_f16rn(c.z, c.w);
            float4 d = r2[q]; wn[2 * q] = pack_f16rn(d.x, d.y); wn[2 * q + 1] = pack_f16rn(d.z, d.w);
            __builtin_amdgcn_sched_barrier(0);
        }
    }

    const float bh0 = bh[j];
    const float bh1 = bh[j + 256];
    const float bh2 = bh[j + 512];

    float hreg = 0.f;
    if (tid < H_) h16[0][tid] = 0;

    float* outp = out + (size_t)b * 512 + dir * 256;
    float* hnp = hn + (size_t)dir * (B_ * H_) + (size_t)b * H_;

    int crow = dir ? ((len - 1) & (T_ - 1)) : 0;   // row of current step
    int prow = dir ? ((len - 2) & (T_ - 1)) : 1;   // row of next step
    const int rstep = dir ? -1 : 1;
    const PT* Pbase = P + (size_t)b * G3 + j;

    // prologue: P for step 0
    float cir, ciz, cin;
    {
        const PT* pp = Pbase + (size_t)crow * (B_ * G3);
        cir = (float)pp[0]; ciz = (float)pp[256]; cin = (float)pp[512];
    }
    sync_lds();

#pragma unroll 1
    for (int s = 0; s < T_; ++s) {
        // prefetch next step's P (stays in flight across the barrier)
        float nir = 0.f, niz = 0.f, nin = 0.f;
        if (s + 1 < T_) {
            const PT* pp = Pbase + (size_t)prow * (B_ * G3);
            nir = (float)pp[0]; niz = (float)pp[256]; nin = (float)pp[512];
        }

        // ---- matvec over this thread's K-half: 192 v_pk_fma_f16 ----
        // Packed accumulators: each f16 half accumulates <=32 terms
        // (|w*h| <= 1/16 -> ~1e-3 RMS), halves summed in f32 below.
        unsigned par0 = 0, par1 = 0, paz0 = 0, paz1 = 0, pan0 = 0, pan1 = 0;
        const uint4* hv = ((const uint4*)h16[s & 1]) + kh * 16;
#pragma unroll
        for (int m = 0; m < 8; ++m) {
            uint4 ua = hv[2 * m];
            uint4 ub = hv[2 * m + 1];
            pkfma(par0, wr[8 * m + 0], ua.x); pkfma(paz0, wz[8 * m + 0], ua.x); pkfma(pan0, wn[8 * m + 0], ua.x);
            pkfma(par1, wr[8 * m + 1], ua.y); pkfma(paz1, wz[8 * m + 1], ua.y); pkfma(pan1, wn[8 * m + 1], ua.y);
            pkfma(par0, wr[8 * m + 2], ua.z); pkfma(paz0, wz[8 * m + 2], ua.z); pkfma(pan0, wn[8 * m + 2], ua.z);
            pkfma(par1, wr[8 * m + 3], ua.w); pkfma(paz1, wz[8 * m + 3], ua.w); pkfma(pan1, wn[8 * m + 3], ua.w);
            pkfma(par0, wr[8 * m + 4], ub.x); pkfma(paz0, wz[8 * m + 4], ub.x); pkfma(pan0, wn[8 * m + 4], ub.x);
            pkfma(par1, wr[8 * m + 5], ub.y); pkfma(paz1, wz[8 * m + 5], ub.y); pkfma(pan1, wn[8 * m + 5], ub.y);
            pkfma(par0, wr[8 * m + 6], ub.z); pkfma(paz0, wz[8 * m + 6], ub.z); pkfma(pan0, wn[8 * m + 6], ub.z);
            pkfma(par1, wr[8 * m + 7], ub.w); pkfma(paz1, wz[8 * m + 7], ub.w); pkfma(pan1, wn[8 * m + 7], ub.w);
            if (m & 1) __builtin_amdgcn_sched_barrier(0);
        }
        float ar = (lo16f(par0) + hi16f(par0)) + (lo16f(par1) + hi16f(par1));
        float az = (lo16f(paz0) + hi16f(paz0)) + (lo16f(paz1) + hi16f(paz1));
        float an = (lo16f(pan0) + hi16f(pan0)) + (lo16f(pan1) + hi16f(pan1));
        // cross-K reduction: partner is lane^32 in the same wave
        ar += __shfl_xor(ar, 32);
        az += __shfl_xor(az, 32);
        an += __shfl_xor(an, 32);

        // ---- epilogue (redundant on both halves; bitwise identical) ----
        float r = sigmoidf_(cir + ar + bh0);
        float z = sigmoidf_(ciz + az + bh1);
        float nng = tanhf_(cin + r * (an + bh2));
        float hnew = (1.f - z) * nng + z * hreg;
        hreg = hnew;

        if (lane < 32) {                   // one half performs the stores
            h16[(s & 1) ^ 1][j] = __half_as_ushort(__float2half_rn(hnew));
            float ov = (do_mask && crow >= len) ? 0.f : hnew;
            outp[(size_t)crow * (B_ * 512) + j] = ov;
            if (s == len - 1) hnp[j] = hnew;
        }
        sync_lds();                        // the ONE barrier per step

        cir = nir; ciz = niz; cin = nin;
        crow = (crow + rstep) & (T_ - 1);
        prow = (prow + rstep) & (T_ - 1);
    }
}

extern "C" void kernel_launch(void* const* d_in, const int* in_sizes, int n_in,
                              void* d_out, int out_size, void* d_ws, size_t ws_size,
                              hipStream_t stream)
{
    const float* x        = (const float*)d_in[0];
    const float* w_ih_l0f = (const float*)d_in[1];
    const float* w_hh_l0f = (const float*)d_in[2];
    const float* b_ih_l0f = (const float*)d_in[3];
    const float* b_hh_l0f = (const float*)d_in[4];
    const float* w_ih_l0b = (const float*)d_in[5];
    const float* w_hh_l0b = (const float*)d_in[6];
    const float* b_ih_l0b = (const float*)d_in[7];
    const float* b_hh_l0b = (const float*)d_in[8];
    const float* w_ih_l1f = (const float*)d_in[9];
    const float* w_hh_l1f = (const float*)d_in[10];
    const float* b_ih_l1f = (const float*)d_in[11];
    const float* b_hh_l1f = (const float*)d_in[12];
    const float* w_ih_l1b = (const float*)d_in[13];
    const float* w_hh_l1b = (const float*)d_in[14];
    const float* b_ih_l1b = (const float*)d_in[15];
    const float* b_hh_l1b = (const float*)d_in[16];
    const int*   lengths  = (const int*)d_in[17];

    float* out = (float*)d_out;
    const size_t OUT_OFF = (size_t)T_ * B_ * 512;
    float* hn0 = out + OUT_OFF;
    float* hn1 = hn0 + 2 * B_ * H_;

    const size_t PE = (size_t)T_ * B_ * G3;
    const int M = T_ * B_;
    dim3 gg(G3 / 64, M / 64);

    if (ws_size >= 2 * PE * sizeof(float)) {
        float* P0 = (float*)d_ws;
        float* P1 = P0 + PE;
        gemm_bias_nt<float><<<gg, 256, 0, stream>>>(x, w_ih_l0f, b_ih_l0f, P0, M, G3, 256);
        gemm_bias_nt<float><<<gg, 256, 0, stream>>>(x, w_ih_l0b, b_ih_l0b, P1, M, G3, 256);
        gru_scan_pk<float><<<64, 512, 0, stream>>>(P0, P1, w_hh_l0f, w_hh_l0b,
                                                   b_hh_l0f, b_hh_l0b, lengths, out, hn0, 0);
        gemm_bias_nt<float><<<gg, 256, 0, stream>>>(out, w_ih_l1f, b_ih_l1f, P0, M, G3, 512);
        gemm_bias_nt<float><<<gg, 256, 0, stream>>>(out, w_ih_l1b, b_ih_l1b, P1, M, G3, 512);
        gru_scan_pk<float><<<64, 512, 0, stream>>>(P0, P1, w_hh_l1f, w_hh_l1b,
                                                   b_hh_l1f, b_hh_l1b, lengths, out, hn1, 1);
    } else if (ws_size >= 2 * PE * sizeof(__hip_bfloat16)) {
        __hip_bfloat16* P0 = (__hip_bfloat16*)d_ws;
        __hip_bfloat16* P1 = P0 + PE;
        gemm_bias_nt<__hip_bfloat16><<<gg, 256, 0, stream>>>(x, w_ih_l0f, b_ih_l0f, P0, M, G3, 256);
        gemm_bias_nt<__hip_bfloat16><<<gg, 256, 0, stream>>>(x, w_ih_l0b, b_ih_l0b, P1, M, G3, 256);
        gru_scan_pk<__hip_bfloat16><<<64, 512, 0, stream>>>(P0, P1, w_hh_l0f, w_hh_l0b,
                                                            b_hh_l0f, b_hh_l0b, lengths, out, hn0, 0);
        gemm_bias_nt<__hip_bfloat16><<<gg, 256, 0, stream>>>(out, w_ih_l1f, b_ih_l1f, P0, M, G3, 512);
        gemm_bias_nt<__hip_bfloat16><<<gg, 256, 0, stream>>>(out, w_ih_l1b, b_ih_l1b, P1, M, G3, 512);
        gru_scan_pk<__hip_bfloat16><<<64, 512, 0, stream>>>(P0, P1, w_hh_l1f, w_hh_l1b,
                                                            b_hh_l1f, b_hh_l1b, lengths, out, hn1, 1);
    }
}

// Round 10
// 3980.570 us; speedup vs baseline: 1.1679x; 1.0014x over previous
//
#include <hip/hip_runtime.h>
#include <hip/hip_bf16.h>
#include <hip/hip_fp16.h>

#define T_ 1024
#define B_ 32
#define H_ 256
#define G3 768   // 3*H

__device__ __forceinline__ float sigmoidf_(float x) { return 1.f / (1.f + __expf(-x)); }
__device__ __forceinline__ float tanhf_(float x) {
    float e = __expf(2.f * x);
    return (e - 1.f) / (e + 1.f);
}

// LDS-only barrier: does NOT drain vmcnt (global prefetch loads / out stores
// stay in flight across it).
__device__ __forceinline__ void sync_lds() {
    asm volatile("s_waitcnt lgkmcnt(0)" ::: "memory");
    asm volatile("s_barrier" ::: "memory");
}

// Packed f16 FMA: acc.{lo,hi} += w.{lo,hi} * h.{lo,hi}  (full-rate VOP3P)
__device__ __forceinline__ void pkfma(unsigned& acc, unsigned w, unsigned h) {
    asm("v_pk_fma_f16 %0, %1, %2, %0" : "+v"(acc) : "v"(w), "v"(h));
}

__device__ __forceinline__ float lo16f(unsigned u) {
    return (float)__ushort_as_half((unsigned short)(u & 0xffffu));
}
__device__ __forceinline__ float hi16f(unsigned u) {
    return (float)__ushort_as_half((unsigned short)(u >> 16));
}

__device__ __forceinline__ unsigned pack_f16rn(float x, float y) {
    unsigned short ux = __half_as_ushort(__float2half_rn(x));
    unsigned short uy = __half_as_ushort(__float2half_rn(y));
    return (unsigned)ux | ((unsigned)uy << 16);
}

// C[M,N] = A[M,K] @ W[N,K]^T + bias[N]
template <typename CT>
__global__ __launch_bounds__(256) void gemm_bias_nt(
    const float* __restrict__ A, const float* __restrict__ W,
    const float* __restrict__ bias, CT* __restrict__ C,
    int M, int N, int K)
{
    __shared__ float As[16][68];
    __shared__ float Ws[16][68];
    const int tid = threadIdx.x;
    const int bm = blockIdx.y * 64;
    const int bn = blockIdx.x * 64;
    const int lr = tid & 63;
    const int lc = tid >> 6;
    const int tx = tid & 15;
    const int ty = tid >> 4;

    const float* Ap = A + (size_t)(bm + lr) * K + lc * 4;
    const float* Wp = W + (size_t)(bn + lr) * K + lc * 4;

    float acc[4][4];
#pragma unroll
    for (int i = 0; i < 4; ++i)
#pragma unroll
        for (int j = 0; j < 4; ++j) acc[i][j] = 0.f;

    for (int k0 = 0; k0 < K; k0 += 16) {
        float4 av = *(const float4*)(Ap + k0);
        float4 wv = *(const float4*)(Wp + k0);
        __syncthreads();
        As[lc * 4 + 0][lr] = av.x; As[lc * 4 + 1][lr] = av.y;
        As[lc * 4 + 2][lr] = av.z; As[lc * 4 + 3][lr] = av.w;
        Ws[lc * 4 + 0][lr] = wv.x; Ws[lc * 4 + 1][lr] = wv.y;
        Ws[lc * 4 + 2][lr] = wv.z; Ws[lc * 4 + 3][lr] = wv.w;
        __syncthreads();
#pragma unroll
        for (int kk = 0; kk < 16; ++kk) {
            float4 a4 = *(const float4*)&As[kk][ty * 4];
            float4 w4 = *(const float4*)&Ws[kk][tx * 4];
            float am[4] = {a4.x, a4.y, a4.z, a4.w};
            float wn[4] = {w4.x, w4.y, w4.z, w4.w};
#pragma unroll
            for (int i = 0; i < 4; ++i)
#pragma unroll
                for (int j = 0; j < 4; ++j) acc[i][j] += am[i] * wn[j];
        }
    }

#pragma unroll
    for (int i = 0; i < 4; ++i) {
        size_t cbase = (size_t)(bm + ty * 4 + i) * N + bn + tx * 4;
#pragma unroll
        for (int j = 0; j < 4; ++j) {
            float v = acc[i][j] + bias[bn + tx * 4 + j];
            C[cbase + j] = (CT)v;
        }
    }
}

// One WG per (batch, direction), 512 threads = 8 waves. Identical to R9
// EXCEPT: a ~100 KB LDS occupancy limiter. With >80 KB LDS only ONE WG fits
// per CU, so the register allocator's achievable occupancy drops to
// 2 waves/SIMD -> VGPR budget 256 -> the 192-reg weight array stays in ARCH
// VGPRs instead of being spilled to AGPRs (v_accvgpr_read per use was the
// suspected ~2.3x VALU expansion). Runtime occupancy is unchanged: we already
// run 1 WG/CU (64 WGs over 64 CUs).
template <typename PT>
__global__ __launch_bounds__(512, 2) void gru_scan_pk(
    const PT* __restrict__ Pf, const PT* __restrict__ Pb,
    const float* __restrict__ Wf, const float* __restrict__ Wb,
    const float* __restrict__ bhf, const float* __restrict__ bhb,
    const int* __restrict__ lengths,
    float* __restrict__ out,   // (T,B,512)
    float* __restrict__ hn,    // [dir][b][j]
    int do_mask)
{
    const int b = blockIdx.x >> 1;
    const int dir = blockIdx.x & 1;
    const PT* P = dir ? Pb : Pf;
    const float* W = dir ? Wb : Wf;
    const float* bh = dir ? bhb : bhf;
    const int len = lengths[b];

    __shared__ __align__(16) unsigned short h16[2][H_];  // double-buffered h
    __shared__ float occ_limit[25600];                   // 100 KB: caps CU at 1 WG

    const int tid = threadIdx.x;
    const int lane = tid & 63;
    const int wave = tid >> 6;
    const int j = wave * 32 + (lane & 31);
    const int kh = lane >> 5;

    if (do_mask < 0) occ_limit[tid] = 0.f;   // never true; keeps LDS alive

    // ---- load W_hh rows j, j+256, j+512 (K-half) into registers ----
    unsigned wr[64], wz[64], wn[64];
    {
        const float4* r0 = (const float4*)(W + (size_t)j * H_ + kh * 128);
        const float4* r1 = (const float4*)(W + (size_t)(j + 256) * H_ + kh * 128);
        const float4* r2 = (const float4*)(W + (size_t)(j + 512) * H_ + kh * 128);
#pragma unroll
        for (int q = 0; q < 32; ++q) {
            float4 a = r0[q]; wr[2 * q] = pack_f16rn(a.x, a.y); wr[2 * q + 1] = pack_f16rn(a.z, a.w);
            float4 c = r1[q]; wz[2 * q] = pack_f16rn(c.x, c.y); wz[2 * q + 1] = pack_f16rn(c.z, c.w);
            float4 d = r2[q]; wn[2 * q] = pack_f16rn(d.x, d.y); wn[2 * q + 1] = pack_f16rn(d.z, d.w);
            __builtin_amdgcn_sched_barrier(0);
        }
    }

    const float bh0 = bh[j];
    const float bh1 = bh[j + 256];
    const float bh2 = bh[j + 512];

    float hreg = 0.f;
    if (tid < H_) h16[0][tid] = 0;

    float* outp = out + (size_t)b * 512 + dir * 256;
    float* hnp = hn + (size_t)dir * (B_ * H_) + (size_t)b * H_;

    int crow = dir ? ((len - 1) & (T_ - 1)) : 0;   // row of current step
    int prow = dir ? ((len - 2) & (T_ - 1)) : 1;   // row of next step
    const int rstep = dir ? -1 : 1;
    const PT* Pbase = P + (size_t)b * G3 + j;

    // prologue: P for step 0
    float cir, ciz, cin;
    {
        const PT* pp = Pbase + (size_t)crow * (B_ * G3);
        cir = (float)pp[0]; ciz = (float)pp[256]; cin = (float)pp[512];
    }
    sync_lds();

#pragma unroll 1
    for (int s = 0; s < T_; ++s) {
        // prefetch next step's P (stays in flight across the barrier)
        float nir = 0.f, niz = 0.f, nin = 0.f;
        if (s + 1 < T_) {
            const PT* pp = Pbase + (size_t)prow * (B_ * G3);
            nir = (float)pp[0]; niz = (float)pp[256]; nin = (float)pp[512];
        }

        // ---- matvec over this thread's K-half: 192 v_pk_fma_f16 ----
        unsigned par0 = 0, par1 = 0, paz0 = 0, paz1 = 0, pan0 = 0, pan1 = 0;
        const uint4* hv = ((const uint4*)h16[s & 1]) + kh * 16;
#pragma unroll
        for (int m = 0; m < 8; ++m) {
            uint4 ua = hv[2 * m];
            uint4 ub = hv[2 * m + 1];
            pkfma(par0, wr[8 * m + 0], ua.x); pkfma(paz0, wz[8 * m + 0], ua.x); pkfma(pan0, wn[8 * m + 0], ua.x);
            pkfma(par1, wr[8 * m + 1], ua.y); pkfma(paz1, wz[8 * m + 1], ua.y); pkfma(pan1, wn[8 * m + 1], ua.y);
            pkfma(par0, wr[8 * m + 2], ua.z); pkfma(paz0, wz[8 * m + 2], ua.z); pkfma(pan0, wn[8 * m + 2], ua.z);
            pkfma(par1, wr[8 * m + 3], ua.w); pkfma(paz1, wz[8 * m + 3], ua.w); pkfma(pan1, wn[8 * m + 3], ua.w);
            pkfma(par0, wr[8 * m + 4], ub.x); pkfma(paz0, wz[8 * m + 4], ub.x); pkfma(pan0, wn[8 * m + 4], ub.x);
            pkfma(par1, wr[8 * m + 5], ub.y); pkfma(paz1, wz[8 * m + 5], ub.y); pkfma(pan1, wn[8 * m + 5], ub.y);
            pkfma(par0, wr[8 * m + 6], ub.z); pkfma(paz0, wz[8 * m + 6], ub.z); pkfma(pan0, wn[8 * m + 6], ub.z);
            pkfma(par1, wr[8 * m + 7], ub.w); pkfma(paz1, wz[8 * m + 7], ub.w); pkfma(pan1, wn[8 * m + 7], ub.w);
            if (m & 1) __builtin_amdgcn_sched_barrier(0);
        }
        float ar = (lo16f(par0) + hi16f(par0)) + (lo16f(par1) + hi16f(par1));
        float az = (lo16f(paz0) + hi16f(paz0)) + (lo16f(paz1) + hi16f(paz1));
        float an = (lo16f(pan0) + hi16f(pan0)) + (lo16f(pan1) + hi16f(pan1));
        // cross-K reduction: partner is lane^32 in the same wave
        ar += __shfl_xor(ar, 32);
        az += __shfl_xor(az, 32);
        an += __shfl_xor(an, 32);

        // ---- epilogue (redundant on both halves; bitwise identical) ----
        float r = sigmoidf_(cir + ar + bh0);
        float z = sigmoidf_(ciz + az + bh1);
        float nng = tanhf_(cin + r * (an + bh2));
        float hnew = (1.f - z) * nng + z * hreg;
        hreg = hnew;

        if (lane < 32) {                   // one half performs the stores
            h16[(s & 1) ^ 1][j] = __half_as_ushort(__float2half_rn(hnew));
            float ov = (do_mask && crow >= len) ? 0.f : hnew;
            outp[(size_t)crow * (B_ * 512) + j] = ov;
            if (s == len - 1) hnp[j] = hnew;
        }
        sync_lds();                        // the ONE barrier per step

        cir = nir; ciz = niz; cin = nin;
        crow = (crow + rstep) & (T_ - 1);
        prow = (prow + rstep) & (T_ - 1);
    }
}

extern "C" void kernel_launch(void* const* d_in, const int* in_sizes, int n_in,
                              void* d_out, int out_size, void* d_ws, size_t ws_size,
                              hipStream_t stream)
{
    const float* x        = (const float*)d_in[0];
    const float* w_ih_l0f = (const float*)d_in[1];
    const float* w_hh_l0f = (const float*)d_in[2];
    const float* b_ih_l0f = (const float*)d_in[3];
    const float* b_hh_l0f = (const float*)d_in[4];
    const float* w_ih_l0b = (const float*)d_in[5];
    const float* w_hh_l0b = (const float*)d_in[6];
    const float* b_ih_l0b = (const float*)d_in[7];
    const float* b_hh_l0b = (const float*)d_in[8];
    const float* w_ih_l1f = (const float*)d_in[9];
    const float* w_hh_l1f = (const float*)d_in[10];
    const float* b_ih_l1f = (const float*)d_in[11];
    const float* b_hh_l1f = (const float*)d_in[12];
    const float* w_ih_l1b = (const float*)d_in[13];
    const float* w_hh_l1b = (const float*)d_in[14];
    const float* b_ih_l1b = (const float*)d_in[15];
    const float* b_hh_l1b = (const float*)d_in[16];
    const int*   lengths  = (const int*)d_in[17];

    float* out = (float*)d_out;
    const size_t OUT_OFF = (size_t)T_ * B_ * 512;
    float* hn0 = out + OUT_OFF;
    float* hn1 = hn0 + 2 * B_ * H_;

    const size_t PE = (size_t)T_ * B_ * G3;
    const int M = T_ * B_;
    dim3 gg(G3 / 64, M / 64);

    if (ws_size >= 2 * PE * sizeof(float)) {
        float* P0 = (float*)d_ws;
        float* P1 = P0 + PE;
        gemm_bias_nt<float><<<gg, 256, 0, stream>>>(x, w_ih_l0f, b_ih_l0f, P0, M, G3, 256);
        gemm_bias_nt<float><<<gg, 256, 0, stream>>>(x, w_ih_l0b, b_ih_l0b, P1, M, G3, 256);
        gru_scan_pk<float><<<64, 512, 0, stream>>>(P0, P1, w_hh_l0f, w_hh_l0b,
                                                   b_hh_l0f, b_hh_l0b, lengths, out, hn0, 0);
        gemm_bias_nt<float><<<gg, 256, 0, stream>>>(out, w_ih_l1f, b_ih_l1f, P0, M, G3, 512);
        gemm_bias_nt<float><<<gg, 256, 0, stream>>>(out, w_ih_l1b, b_ih_l1b, P1, M, G3, 512);
        gru_scan_pk<float><<<64, 512, 0, stream>>>(P0, P1, w_hh_l1f, w_hh_l1b,
                                                   b_hh_l1f, b_hh_l1b, lengths, out, hn1, 1);
    } else if (ws_size >= 2 * PE * sizeof(__hip_bfloat16)) {
        __hip_bfloat16* P0 = (__hip_bfloat16*)d_ws;
        __hip_bfloat16* P1 = P0 + PE;
        gemm_bias_nt<__hip_bfloat16><<<gg, 256, 0, stream>>>(x, w_ih_l0f, b_ih_l0f, P0, M, G3, 256);
        gemm_bias_nt<__hip_bfloat16><<<gg, 256, 0, stream>>>(x, w_ih_l0b, b_ih_l0b, P1, M, G3, 256);
        gru_scan_pk<__hip_bfloat16><<<64, 512, 0, stream>>>(P0, P1, w_hh_l0f, w_hh_l0b,
                                                            b_hh_l0f, b_hh_l0b, lengths, out, hn0, 0);
        gemm_bias_nt<__hip_bfloat16><<<gg, 256, 0, stream>>>(out, w_ih_l1f, b_ih_l1f, P0, M, G3, 512);
        gemm_bias_nt<__hip_bfloat16><<<gg, 256, 0, stream>>>(out, w_ih_l1b, b_ih_l1b, P1, M, G3, 512);
        gru_scan_pk<__hip_bfloat16><<<64, 512, 0, stream>>>(P0, P1, w_hh_l1f, w_hh_l1b,
                                                            b_hh_l1f, b_hh_l1b, lengths, out, hn1, 1);
    }
}

// Round 11
// 3974.730 us; speedup vs baseline: 1.1696x; 1.0015x over previous
//
#include <hip/hip_runtime.h>
#include <hip/hip_bf16.h>
#include <hip/hip_fp16.h>

#define T_ 1024
#define B_ 32
#define H_ 256
#define G3 768   // 3*H

__device__ __forceinline__ float sigmoidf_(float x) { return 1.f / (1.f + __expf(-x)); }
__device__ __forceinline__ float tanhf_(float x) {
    float e = __expf(2.f * x);
    return (e - 1.f) / (e + 1.f);
}

// LDS-only barrier: does NOT drain vmcnt (global prefetch loads / out stores
// stay in flight across it).
__device__ __forceinline__ void sync_lds() {
    asm volatile("s_waitcnt lgkmcnt(0)" ::: "memory");
    asm volatile("s_barrier" ::: "memory");
}

// Packed f16 FMA: acc.{lo,hi} += w.{lo,hi} * h.{lo,hi}  (full-rate VOP3P)
__device__ __forceinline__ void pkfma(unsigned& acc, unsigned w, unsigned h) {
    asm("v_pk_fma_f16 %0, %1, %2, %0" : "+v"(acc) : "v"(w), "v"(h));
}

__device__ __forceinline__ float lo16f(unsigned u) {
    return (float)__ushort_as_half((unsigned short)(u & 0xffffu));
}
__device__ __forceinline__ float hi16f(unsigned u) {
    return (float)__ushort_as_half((unsigned short)(u >> 16));
}

__device__ __forceinline__ unsigned pack_f16rn(float x, float y) {
    unsigned short ux = __half_as_ushort(__float2half_rn(x));
    unsigned short uy = __half_as_ushort(__float2half_rn(y));
    return (unsigned)ux | ((unsigned)uy << 16);
}

// C[M,N] = A[M,K] @ W[N,K]^T + bias[N]
template <typename CT>
__global__ __launch_bounds__(256) void gemm_bias_nt(
    const float* __restrict__ A, const float* __restrict__ W,
    const float* __restrict__ bias, CT* __restrict__ C,
    int M, int N, int K)
{
    __shared__ float As[16][68];
    __shared__ float Ws[16][68];
    const int tid = threadIdx.x;
    const int bm = blockIdx.y * 64;
    const int bn = blockIdx.x * 64;
    const int lr = tid & 63;
    const int lc = tid >> 6;
    const int tx = tid & 15;
    const int ty = tid >> 4;

    const float* Ap = A + (size_t)(bm + lr) * K + lc * 4;
    const float* Wp = W + (size_t)(bn + lr) * K + lc * 4;

    float acc[4][4];
#pragma unroll
    for (int i = 0; i < 4; ++i)
#pragma unroll
        for (int j = 0; j < 4; ++j) acc[i][j] = 0.f;

    for (int k0 = 0; k0 < K; k0 += 16) {
        float4 av = *(const float4*)(Ap + k0);
        float4 wv = *(const float4*)(Wp + k0);
        __syncthreads();
        As[lc * 4 + 0][lr] = av.x; As[lc * 4 + 1][lr] = av.y;
        As[lc * 4 + 2][lr] = av.z; As[lc * 4 + 3][lr] = av.w;
        Ws[lc * 4 + 0][lr] = wv.x; Ws[lc * 4 + 1][lr] = wv.y;
        Ws[lc * 4 + 2][lr] = wv.z; Ws[lc * 4 + 3][lr] = wv.w;
        __syncthreads();
#pragma unroll
        for (int kk = 0; kk < 16; ++kk) {
            float4 a4 = *(const float4*)&As[kk][ty * 4];
            float4 w4 = *(const float4*)&Ws[kk][tx * 4];
            float am[4] = {a4.x, a4.y, a4.z, a4.w};
            float wn[4] = {w4.x, w4.y, w4.z, w4.w};
#pragma unroll
            for (int i = 0; i < 4; ++i)
#pragma unroll
                for (int j = 0; j < 4; ++j) acc[i][j] += am[i] * wn[j];
        }
    }

#pragma unroll
    for (int i = 0; i < 4; ++i) {
        size_t cbase = (size_t)(bm + ty * 4 + i) * N + bn + tx * 4;
#pragma unroll
        for (int j = 0; j < 4; ++j) {
            float v = acc[i][j] + bias[bn + tx * 4 + j];
            C[cbase + j] = (CT)v;
        }
    }
}

// One WG per (batch, direction), 512 threads = 8 waves. Identical to R10
// EXCEPT __launch_bounds__(512, 1): observed allocator heuristic budgets
// VGPRs for 2x the declared MIN waves/EU (R8: min4->64regs, R3-R10:
// min2->128regs). min=1 -> 2 waves/EU target -> 256-VGPR budget -> the
// 192-reg weight array finally fits in ARCH VGPRs (no ACC-copy per use).
// The 100 KB LDS limiter keeps runtime occupancy at the same 1 WG/CU.
template <typename PT>
__global__ __launch_bounds__(512, 1) void gru_scan_pk(
    const PT* __restrict__ Pf, const PT* __restrict__ Pb,
    const float* __restrict__ Wf, const float* __restrict__ Wb,
    const float* __restrict__ bhf, const float* __restrict__ bhb,
    const int* __restrict__ lengths,
    float* __restrict__ out,   // (T,B,512)
    float* __restrict__ hn,    // [dir][b][j]
    int do_mask)
{
    const int b = blockIdx.x >> 1;
    const int dir = blockIdx.x & 1;
    const PT* P = dir ? Pb : Pf;
    const float* W = dir ? Wb : Wf;
    const float* bh = dir ? bhb : bhf;
    const int len = lengths[b];

    __shared__ __align__(16) unsigned short h16[2][H_];  // double-buffered h
    __shared__ float occ_limit[25600];                   // 100 KB: caps CU at 1 WG

    const int tid = threadIdx.x;
    const int lane = tid & 63;
    const int wave = tid >> 6;
    const int j = wave * 32 + (lane & 31);
    const int kh = lane >> 5;

    if (do_mask < 0) occ_limit[tid] = 0.f;   // never true; keeps LDS alive

    // ---- load W_hh rows j, j+256, j+512 (K-half) into registers ----
    unsigned wr[64], wz[64], wn[64];
    {
        const float4* r0 = (const float4*)(W + (size_t)j * H_ + kh * 128);
        const float4* r1 = (const float4*)(W + (size_t)(j + 256) * H_ + kh * 128);
        const float4* r2 = (const float4*)(W + (size_t)(j + 512) * H_ + kh * 128);
#pragma unroll
        for (int q = 0; q < 32; ++q) {
            float4 a = r0[q]; wr[2 * q] = pack_f16rn(a.x, a.y); wr[2 * q + 1] = pack_f16rn(a.z, a.w);
            float4 c = r1[q]; wz[2 * q] = pack_f16rn(c.x, c.y); wz[2 * q + 1] = pack_f16rn(c.z, c.w);
            float4 d = r2[q]; wn[2 * q] = pack_f16rn(d.x, d.y); wn[2 * q + 1] = pack_f16rn(d.z, d.w);
            __builtin_amdgcn_sched_barrier(0);
        }
    }

    const float bh0 = bh[j];
    const float bh1 = bh[j + 256];
    const float bh2 = bh[j + 512];

    float hreg = 0.f;
    if (tid < H_) h16[0][tid] = 0;

    float* outp = out + (size_t)b * 512 + dir * 256;
    float* hnp = hn + (size_t)dir * (B_ * H_) + (size_t)b * H_;

    int crow = dir ? ((len - 1) & (T_ - 1)) : 0;   // row of current step
    int prow = dir ? ((len - 2) & (T_ - 1)) : 1;   // row of next step
    const int rstep = dir ? -1 : 1;
    const PT* Pbase = P + (size_t)b * G3 + j;

    // prologue: P for step 0
    float cir, ciz, cin;
    {
        const PT* pp = Pbase + (size_t)crow * (B_ * G3);
        cir = (float)pp[0]; ciz = (float)pp[256]; cin = (float)pp[512];
    }
    sync_lds();

#pragma unroll 1
    for (int s = 0; s < T_; ++s) {
        // prefetch next step's P (stays in flight across the barrier)
        float nir = 0.f, niz = 0.f, nin = 0.f;
        if (s + 1 < T_) {
            const PT* pp = Pbase + (size_t)prow * (B_ * G3);
            nir = (float)pp[0]; niz = (float)pp[256]; nin = (float)pp[512];
        }

        // ---- matvec over this thread's K-half: 192 v_pk_fma_f16 ----
        unsigned par0 = 0, par1 = 0, paz0 = 0, paz1 = 0, pan0 = 0, pan1 = 0;
        const uint4* hv = ((const uint4*)h16[s & 1]) + kh * 16;
#pragma unroll
        for (int m = 0; m < 8; ++m) {
            uint4 ua = hv[2 * m];
            uint4 ub = hv[2 * m + 1];
            pkfma(par0, wr[8 * m + 0], ua.x); pkfma(paz0, wz[8 * m + 0], ua.x); pkfma(pan0, wn[8 * m + 0], ua.x);
            pkfma(par1, wr[8 * m + 1], ua.y); pkfma(paz1, wz[8 * m + 1], ua.y); pkfma(pan1, wn[8 * m + 1], ua.y);
            pkfma(par0, wr[8 * m + 2], ua.z); pkfma(paz0, wz[8 * m + 2], ua.z); pkfma(pan0, wn[8 * m + 2], ua.z);
            pkfma(par1, wr[8 * m + 3], ua.w); pkfma(paz1, wz[8 * m + 3], ua.w); pkfma(pan1, wn[8 * m + 3], ua.w);
            pkfma(par0, wr[8 * m + 4], ub.x); pkfma(paz0, wz[8 * m + 4], ub.x); pkfma(pan0, wn[8 * m + 4], ub.x);
            pkfma(par1, wr[8 * m + 5], ub.y); pkfma(paz1, wz[8 * m + 5], ub.y); pkfma(pan1, wn[8 * m + 5], ub.y);
            pkfma(par0, wr[8 * m + 6], ub.z); pkfma(paz0, wz[8 * m + 6], ub.z); pkfma(pan0, wn[8 * m + 6], ub.z);
            pkfma(par1, wr[8 * m + 7], ub.w); pkfma(paz1, wz[8 * m + 7], ub.w); pkfma(pan1, wn[8 * m + 7], ub.w);
            if (m & 1) __builtin_amdgcn_sched_barrier(0);
        }
        float ar = (lo16f(par0) + hi16f(par0)) + (lo16f(par1) + hi16f(par1));
        float az = (lo16f(paz0) + hi16f(paz0)) + (lo16f(paz1) + hi16f(paz1));
        float an = (lo16f(pan0) + hi16f(pan0)) + (lo16f(pan1) + hi16f(pan1));
        // cross-K reduction: partner is lane^32 in the same wave
        ar += __shfl_xor(ar, 32);
        az += __shfl_xor(az, 32);
        an += __shfl_xor(an, 32);

        // ---- epilogue (redundant on both halves; bitwise identical) ----
        float r = sigmoidf_(cir + ar + bh0);
        float z = sigmoidf_(ciz + az + bh1);
        float nng = tanhf_(cin + r * (an + bh2));
        float hnew = (1.f - z) * nng + z * hreg;
        hreg = hnew;

        if (lane < 32) {                   // one half performs the stores
            h16[(s & 1) ^ 1][j] = __half_as_ushort(__float2half_rn(hnew));
            float ov = (do_mask && crow >= len) ? 0.f : hnew;
            outp[(size_t)crow * (B_ * 512) + j] = ov;
            if (s == len - 1) hnp[j] = hnew;
        }
        sync_lds();                        // the ONE barrier per step

        cir = nir; ciz = niz; cin = nin;
        crow = (crow + rstep) & (T_ - 1);
        prow = (prow + rstep) & (T_ - 1);
    }
}

extern "C" void kernel_launch(void* const* d_in, const int* in_sizes, int n_in,
                              void* d_out, int out_size, void* d_ws, size_t ws_size,
                              hipStream_t stream)
{
    const float* x        = (const float*)d_in[0];
    const float* w_ih_l0f = (const float*)d_in[1];
    const float* w_hh_l0f = (const float*)d_in[2];
    const float* b_ih_l0f = (const float*)d_in[3];
    const float* b_hh_l0f = (const float*)d_in[4];
    const float* w_ih_l0b = (const float*)d_in[5];
    const float* w_hh_l0b = (const float*)d_in[6];
    const float* b_ih_l0b = (const float*)d_in[7];
    const float* b_hh_l0b = (const float*)d_in[8];
    const float* w_ih_l1f = (const float*)d_in[9];
    const float* w_hh_l1f = (const float*)d_in[10];
    const float* b_ih_l1f = (const float*)d_in[11];
    const float* b_hh_l1f = (const float*)d_in[12];
    const float* w_ih_l1b = (const float*)d_in[13];
    const float* w_hh_l1b = (const float*)d_in[14];
    const float* b_ih_l1b = (const float*)d_in[15];
    const float* b_hh_l1b = (const float*)d_in[16];
    const int*   lengths  = (const int*)d_in[17];

    float* out = (float*)d_out;
    const size_t OUT_OFF = (size_t)T_ * B_ * 512;
    float* hn0 = out + OUT_OFF;
    float* hn1 = hn0 + 2 * B_ * H_;

    const size_t PE = (size_t)T_ * B_ * G3;
    const int M = T_ * B_;
    dim3 gg(G3 / 64, M / 64);

    if (ws_size >= 2 * PE * sizeof(float)) {
        float* P0 = (float*)d_ws;
        float* P1 = P0 + PE;
        gemm_bias_nt<float><<<gg, 256, 0, stream>>>(x, w_ih_l0f, b_ih_l0f, P0, M, G3, 256);
        gemm_bias_nt<float><<<gg, 256, 0, stream>>>(x, w_ih_l0b, b_ih_l0b, P1, M, G3, 256);
        gru_scan_pk<float><<<64, 512, 0, stream>>>(P0, P1, w_hh_l0f, w_hh_l0b,
                                                   b_hh_l0f, b_hh_l0b, lengths, out, hn0, 0);
        gemm_bias_nt<float><<<gg, 256, 0, stream>>>(out, w_ih_l1f, b_ih_l1f, P0, M, G3, 512);
        gemm_bias_nt<float><<<gg, 256, 0, stream>>>(out, w_ih_l1b, b_ih_l1b, P1, M, G3, 512);
        gru_scan_pk<float><<<64, 512, 0, stream>>>(P0, P1, w_hh_l1f, w_hh_l1b,
                                                   b_hh_l1f, b_hh_l1b, lengths, out, hn1, 1);
    } else if (ws_size >= 2 * PE * sizeof(__hip_bfloat16)) {
        __hip_bfloat16* P0 = (__hip_bfloat16*)d_ws;
        __hip_bfloat16* P1 = P0 + PE;
        gemm_bias_nt<__hip_bfloat16><<<gg, 256, 0, stream>>>(x, w_ih_l0f, b_ih_l0f, P0, M, G3, 256);
        gemm_bias_nt<__hip_bfloat16><<<gg, 256, 0, stream>>>(x, w_ih_l0b, b_ih_l0b, P1, M, G3, 256);
        gru_scan_pk<__hip_bfloat16><<<64, 512, 0, stream>>>(P0, P1, w_hh_l0f, w_hh_l0b,
                                                            b_hh_l0f, b_hh_l0b, lengths, out, hn0, 0);
        gemm_bias_nt<__hip_bfloat16><<<gg, 256, 0, stream>>>(out, w_ih_l1f, b_ih_l1f, P0, M, G3, 512);
        gemm_bias_nt<__hip_bfloat16><<<gg, 256, 0, stream>>>(out, w_ih_l1b, b_ih_l1b, P1, M, G3, 512);
        gru_scan_pk<__hip_bfloat16><<<64, 512, 0, stream>>>(P0, P1, w_hh_l1f, w_hh_l1b,
                                                            b_hh_l1f, b_hh_l1b, lengths, out, hn1, 1);
    }
}